// Round 2
// 7377.046 us; speedup vs baseline: 1.4626x; 1.4626x over previous
//
#include <hip/hip_runtime.h>
#include <hip/hip_bf16.h>
#include <stdint.h>

// Round 2: hardened store/flag grid barrier — wave0-only poll + s_sleep backoff
// + bounded spin (hang -> wrong-answer signal instead of dead container).
// Direct-global h fragments, prefetch hoisted above the wait, one release fence
// + relaxed flag store per step (no RMWs). B=8 T=512 F=1024 V=32000.

typedef __attribute__((ext_vector_type(8))) short short8v;   // 8 bf16 (4 VGPRs)
typedef __attribute__((ext_vector_type(4))) float f32x4;

#define Fd 1024
#define Gd 4096     // 4*F
#define BT 4096     // B*T
#define Tn 512
#define Vd 32000

__device__ __forceinline__ ushort f2bf(float f){
  union { float f; uint32_t u; } v; v.f = f;
  uint32_t u = v.u;
  return (ushort)((u + 0x7fffu + ((u >> 16) & 1u)) >> 16);   // RNE, finite inputs
}

// ---------------- transpose + cast: src[R][C] f32 -> dst[C][R] bf16 ----------------
__global__ __launch_bounds__(256) void transpose_cast(const float* __restrict__ src,
                                                      ushort* __restrict__ dst,
                                                      int R, int C){
  __shared__ float tile[32][33];                 // +1 pad: conflict-free
  int x = threadIdx.x & 31, y = threadIdx.x >> 5;
  int c0 = blockIdx.x * 32, r0 = blockIdx.y * 32;
#pragma unroll
  for (int j = 0; j < 4; ++j){
    int r = r0 + y + j*8;
    tile[y + j*8][x] = src[(size_t)r * C + c0 + x];
  }
  __syncthreads();
#pragma unroll
  for (int j = 0; j < 4; ++j){
    int c = c0 + y + j*8;
    dst[(size_t)c * R + r0 + x] = f2bf(tile[x][y + j*8]);
  }
}

// ---------------- embed gather + cast to bf16: xb[BT][Fd] ----------------
__global__ __launch_bounds__(256) void gather_cast(const int* __restrict__ tokens,
                                                   const float* __restrict__ embed,
                                                   ushort* __restrict__ xb){
  int row = blockIdx.x;
  int tk = tokens[row];
  float4 v = ((const float4*)(embed + (size_t)tk * Fd))[threadIdx.x];
  ushort4 o;
  o.x = f2bf(v.x); o.y = f2bf(v.y); o.z = f2bf(v.z); o.w = f2bf(v.w);
  *(ushort4*)(xb + (size_t)row * Fd + threadIdx.x * 4) = o;
}

// ---------------- async global->LDS, 16B per lane ----------------
__device__ __forceinline__ void gl_lds16(const void* g, void* l){
  __builtin_amdgcn_global_load_lds((const __attribute__((address_space(1))) void*)g,
                                   (__attribute__((address_space(3))) void*)l, 16, 0, 0);
}

// ---------------- C[M][N] f32 = A[M][K]bf16 @ Bt[N][K]bf16^T + bias[N] ----------------
// 128x128 tile, 4 waves in 2x2, each wave 4x4 MFMA 16x16x32 tiles (m97 structure).
__global__ __launch_bounds__(256) void gemm_bt(const ushort* __restrict__ A,
                                               const ushort* __restrict__ Bt,
                                               const float* __restrict__ bias,
                                               float* __restrict__ C,
                                               int M, int N, int K, int mtiles){
  __shared__ __align__(16) ushort As[128*32];
  __shared__ __align__(16) ushort Bs[128*32];
  int tid = threadIdx.x, lane = tid & 63, w = tid >> 6;
  int mt0 = (blockIdx.x % mtiles) * 128;
  int nt0 = (blockIdx.x / mtiles) * 128;
  int wm = (w >> 1) * 64, wn = (w & 1) * 64;
  int fr = lane & 15, q = lane >> 4;

  f32x4 acc[4][4];
#pragma unroll
  for (int i = 0; i < 4; ++i)
#pragma unroll
    for (int j = 0; j < 4; ++j) acc[i][j] = (f32x4){0.f,0.f,0.f,0.f};

  int srow  = w*32 + (lane >> 2);          // staging row (call 0); +16 for call 1
  int skoff = (lane & 3) * 8;              // ushort offset in row
  const ushort* gA = A  + (size_t)(mt0 + srow) * K + skoff;
  const ushort* gB = Bt + (size_t)(nt0 + srow) * K + skoff;
  ushort* lA0 = As + (w*32)*32;            // wave-uniform LDS bases
  ushort* lB0 = Bs + (w*32)*32;

  for (int k0 = 0; k0 < K; k0 += 32){
    gl_lds16(gA + k0,                 lA0);
    gl_lds16(gA + (size_t)16*K + k0,  lA0 + 16*32);
    gl_lds16(gB + k0,                 lB0);
    gl_lds16(gB + (size_t)16*K + k0,  lB0 + 16*32);
    __syncthreads();                       // compiler drains vmcnt before barrier
    short8v a[4], b[4];
#pragma unroll
    for (int i = 0; i < 4; ++i){
      a[i] = *(const short8v*)(As + (wm + i*16 + fr)*32 + q*8);
      b[i] = *(const short8v*)(Bs + (wn + i*16 + fr)*32 + q*8);
    }
#pragma unroll
    for (int i = 0; i < 4; ++i)
#pragma unroll
      for (int j = 0; j < 4; ++j)
        acc[i][j] = __builtin_amdgcn_mfma_f32_16x16x32_bf16(a[i], b[j], acc[i][j], 0, 0, 0);
    __syncthreads();
  }
#pragma unroll
  for (int j = 0; j < 4; ++j){
    int col = nt0 + wn + j*16 + fr;
    float bv = bias[col];
#pragma unroll
    for (int i = 0; i < 4; ++i){
      int rbase = mt0 + wm + i*16 + q*4;   // C/D: row=quad*4+reg, col=lane&15 (m89)
#pragma unroll
      for (int r = 0; r < 4; ++r)
        C[(size_t)(rbase + r) * N + col] = acc[i][j][r] + bv;
    }
  }
}

// ---------------- persistent LSTM scan ----------------
// 256 wgs x 256 thr. wg owns features f0=wg*4..+4 (16 gate cols). Wh slice in LDS
// (bf16, stride 1032) for all 512 steps. Per step:
//   prefetch B-frags (LDS) + xW (global)   [barrier-independent]
//   wave0 polls all 256 per-wg flags (relaxed sc1 loads, s_sleep backoff,
//     bounded spin), ONE acquire fence, __syncthreads releases waves 1-3
//     (one-thread-fence + flash-inv pattern, validated by round-0 kernel)
//   h A-frags DIRECT from global hbuf -> MFMA -> LDS reduce -> gates -> h write
//   __syncthreads -> tid0: ONE release fence + relaxed flag store (no RMW)
__global__ __launch_bounds__(256) void lstm_scan(const float* __restrict__ xW,
                                                 const ushort* __restrict__ WhT,  // [4096][1024]
                                                 ushort* __restrict__ hbuf,       // [2][8][1024], zeroed
                                                 ushort* __restrict__ hs,         // [4096][1024]
                                                 int* __restrict__ bar){          // [256], zeroed
  __shared__ __align__(16) ushort Whs[16*1032];
  __shared__ __align__(16) float  pbuf[4*64*4];
  __shared__ float zsmall[8*16];
  __shared__ float act[4*32];

  const int tid = threadIdx.x;
  const int lane = tid & 63, w = tid >> 6;
  const int wg = blockIdx.x;
  const int f0 = wg * 4;
  const int fr = lane & 15, q = lane >> 4;

  // Load Wh slice once: local col n = gate*4+ff -> global col gate*1024 + f0 + ff
#pragma unroll
  for (int jj = 0; jj < 8; ++jj){
    int cch = tid + jj*256;                  // 16 rows * 128 x 16B chunks
    int n = cch >> 7, ch = cch & 127;
    int gc = (n >> 2) * Fd + f0 + (n & 3);
    *(uint4*)(Whs + n*1032 + ch*8) = *(const uint4*)(WhT + (size_t)gc*Fd + ch*8);
  }
  __syncthreads();                           // Whs ready before first b-frag read

  float c_state = 0.f;                       // owned by tid<32: (b=tid>>2, ff=tid&3)
  const ushort* bp = Whs + fr*1032 + q*8 + w*256;

  for (int t = 0; t < Tn; ++t){
    // B-fragments from persistent LDS: no dependency on the barrier — load first
    short8v bfr[8];
#pragma unroll
    for (int kk = 0; kk < 8; ++kk)
      bfr[kk] = *(const short8v*)(bp + kk*32);

    // xW_t prefetch (no dependency on the barrier)
    float xwv = 0.f;
    if (tid < 128){
      int g = tid >> 5, b = (tid >> 2) & 7, ff = tid & 3;
      xwv = xW[(size_t)(b*Tn + t) * Gd + g*Fd + f0 + ff];
    }

    // ---- wait for h_t: wave 0 polls all 256 per-wg flags, others park at barrier
    if (t > 0){
      if (w == 0){
        int* f4 = bar + (lane << 2);         // lane covers flags[4*lane .. 4*lane+3]
        int spins = 0;
        for (;;){
          int v0 = __hip_atomic_load(f4,     __ATOMIC_RELAXED, __HIP_MEMORY_SCOPE_AGENT);
          int v1 = __hip_atomic_load(f4 + 1, __ATOMIC_RELAXED, __HIP_MEMORY_SCOPE_AGENT);
          int v2 = __hip_atomic_load(f4 + 2, __ATOMIC_RELAXED, __HIP_MEMORY_SCOPE_AGENT);
          int v3 = __hip_atomic_load(f4 + 3, __ATOMIC_RELAXED, __HIP_MEMORY_SCOPE_AGENT);
          int mn  = v0 < v1 ? v0 : v1;
          int mn2 = v2 < v3 ? v2 : v3;
          mn = mn < mn2 ? mn : mn2;
          if (__all(mn >= t)) break;
          if (++spins > (1 << 18)) break;    // liveness guard: wrong answer > hang
          __builtin_amdgcn_s_sleep(1);       // backoff: don't hammer the MALL
        }
        __builtin_amdgcn_fence(__ATOMIC_ACQUIRE, "agent");  // one inv per wg per step
      }
      __syncthreads();                       // releases waves 1-3 after inv
    }

    // ---- h A-frags direct from global (rows 8-15 alias rows 0-7, harmless) ----
    const ushort* hsrc = hbuf + (size_t)(t & 1) * (8*Fd) + (fr & 7)*Fd + w*256 + q*8;
    f32x4 pacc = (f32x4){0.f,0.f,0.f,0.f};
#pragma unroll
    for (int kk = 0; kk < 8; ++kk){
      short8v av = *(const short8v*)(hsrc + kk*32);
      pacc = __builtin_amdgcn_mfma_f32_16x16x32_bf16(av, bfr[kk], pacc, 0, 0, 0);
    }
    *(f32x4*)(pbuf + (w*64 + lane)*4) = pacc;
    __syncthreads();

    if (tid < 32){                           // reduce 4 K-slices; rows 0-7 only
      f32x4 s = *(const f32x4*)(pbuf + tid*4);
      s += *(const f32x4*)(pbuf + (64  + tid)*4);
      s += *(const f32x4*)(pbuf + (128 + tid)*4);
      s += *(const f32x4*)(pbuf + (192 + tid)*4);
      int row0 = (tid >> 4) * 4, colz = tid & 15;
#pragma unroll
      for (int r = 0; r < 4; ++r) zsmall[(row0 + r)*16 + colz] = s[r];
    }
    __syncthreads();

    if (tid < 128){                          // gate order i,f,g,o ; tanh on g
      int g = tid >> 5, b = (tid >> 2) & 7, ff = tid & 3;
      float z = zsmall[b*16 + g*4 + ff] + xwv;
      act[g*32 + b*4 + ff] = (g == 2) ? tanhf(z) : 1.f / (1.f + expf(-z));
    }
    __syncthreads();

    if (tid < 32){
      int b = tid >> 2, ff = tid & 3;
      float ai = act[tid], af = act[32 + tid], ag = act[64 + tid], ao = act[96 + tid];
      c_state = af * c_state + ai * ag;
      float h = ao * tanhf(c_state);
      ushort hb = f2bf(h);
      hbuf[(size_t)((t+1) & 1) * (8*Fd) + b*Fd + f0 + ff] = hb;
      hs[(size_t)(b*Tn + t) * Fd + f0 + ff] = hb;
    }

    // ---- publish: syncthreads orders wave0's h stores before tid0's release
    // fence (vmcnt drain + wbl2); relaxed flag store is the release operation
    // observed by the relaxed polls + acquire fence above. ----
    __syncthreads();
    if (tid == 0){
      __builtin_amdgcn_fence(__ATOMIC_RELEASE, "agent");
      __hip_atomic_store(bar + wg, t + 1, __ATOMIC_RELAXED, __HIP_MEMORY_SCOPE_AGENT);
    }
  }
}

extern "C" void kernel_launch(void* const* d_in, const int* in_sizes, int n_in,
                              void* d_out, int out_size, void* d_ws, size_t ws_size,
                              hipStream_t stream){
  const int*   tokens = (const int*)  d_in[0];   // [8][512]
  const float* embed  = (const float*)d_in[1];   // [32001][1024]
  const float* Wx     = (const float*)d_in[2];   // [1024][4096]
  const float* Wh     = (const float*)d_in[3];   // [1024][4096]
  const float* bias   = (const float*)d_in[4];   // [4096]
  const float* Wd     = (const float*)d_in[5];   // [1024][32000]
  const float* bd     = (const float*)d_in[6];   // [32000]
  float* out = (float*)d_out;                    // [4096][32000]

  char* ws = (char*)d_ws;
  float*  xW   = (float*) (ws);                  // 67,108,864  xW fp32 [4096][4096]
  ushort* WxT  = (ushort*)(ws + 67108864);       //  8,388,608  [4096][1024] bf16
  ushort* WhT  = (ushort*)(ws + 75497472);       //  8,388,608  [4096][1024] bf16
  ushort* WdT  = (ushort*)(ws + 83886080);       // 65,536,000  [32000][1024] bf16
  ushort* xb   = (ushort*)(ws + 149422080);      //  8,388,608  [4096][1024] bf16
  ushort* hsb  = (ushort*)(ws + 157810688);      //  8,388,608  [4096][1024] bf16
  ushort* hbuf = (ushort*)(ws + 166199296);      //     32,768  [2][8][1024] bf16
  int*    bar  = (int*)   (ws + 166232064);      //      4,096

  hipMemsetAsync(hbuf, 0, 32768 + 4096, stream); // h0=0, flags=0

  transpose_cast<<<dim3(Gd/32, Fd/32), 256, 0, stream>>>(Wx, WxT, Fd, Gd);
  transpose_cast<<<dim3(Gd/32, Fd/32), 256, 0, stream>>>(Wh, WhT, Fd, Gd);
  transpose_cast<<<dim3(Vd/32, Fd/32), 256, 0, stream>>>(Wd, WdT, Fd, Vd);
  gather_cast<<<BT, 256, 0, stream>>>(tokens, embed, xb);

  gemm_bt<<<(BT/128)*(Gd/128), 256, 0, stream>>>(xb,  WxT, bias, xW,  BT, Gd, Fd, BT/128);
  lstm_scan<<<256, 256, 0, stream>>>(xW, WhT, hbuf, hsb, bar);
  gemm_bt<<<(BT/128)*(Vd/128), 256, 0, stream>>>(hsb, WdT, bd,   out, BT, Vd, Fd, BT/128);
}